// Round 10
// baseline (48.445 us; speedup 1.0000x reference)
//
#include <hip/hip_runtime.h>

// CNS residuals: vars (B=8, C=4, T=64, X=128, Y=128) f32
// out (B=8, 2, 62, 126, 126) f32: [mass, mom_x+mom_y] inner region.
// R10 = R9 body + persistent grid-stride blocks.
// 1024 blocks (4/CU) loop over ~7.6 tile-units each (tile = 8 half-wave
// groups = R9's per-block work). Eliminates block launch/drain ramp, keeps
// waves resident, hoists scalar setup, consecutive xp iterations reuse L1/L2.
// XCD-contiguous: lb=(i&7)*128+(i>>3); tiles [lb*7812>>10,(lb+1)*7812>>10).
// Half-wave x-row sharing (shfl_xor 32) + aligned x-loads + NT stores kept.

typedef float vf4 __attribute__((ext_vector_type(4)));
typedef float vf4u __attribute__((ext_vector_type(4), aligned(4)));

__device__ __forceinline__ vf4 ld4(const float* p) {
    return *reinterpret_cast<const vf4u*>(p);
}

struct Win { vf4 lo, hi; };
// window covers y' = 4j-1 .. 4j+6; output elem e at shift s -> index 2+e+s
#define SH(w, s) __builtin_shufflevector((w).lo, (w).hi, 2 + (s), 3 + (s), 4 + (s), 5 + (s))

__device__ __forceinline__ Win mkwin(vf4 c, float mHi) {
    const float dn0 = __shfl_down(c.x, 1) * mHi;
    const float dn1 = __shfl_down(c.y, 1) * mHi;
    Win w;
    w.lo = (vf4){0.0f, c.x, c.y, c.z};
    w.hi = (vf4){c.w, dn0, dn1, 0.0f};
    return w;
}
__device__ __forceinline__ Win mkwin2(vf4 c, float mLo, float mHi) {
    const float up3 = __shfl_up(c.w, 1) * mLo;
    const float dn0 = __shfl_down(c.x, 1) * mHi;
    const float dn1 = __shfl_down(c.y, 1) * mHi;
    const float dn2 = __shfl_down(c.z, 1) * mHi;
    Win w;
    w.lo = (vf4){up3, c.x, c.y, c.z};
    w.hi = (vf4){c.w, dn0, dn1, dn2};
    return w;
}
__device__ __forceinline__ vf4 ctrf(vf4 c, float mHi) {
    const float dn0 = __shfl_down(c.x, 1) * mHi;
    return (vf4){c.y, c.z, c.w, dn0};
}
__device__ __forceinline__ vf4 swap4(vf4 c) {
    vf4 r;
    r.x = __shfl_xor(c.x, 32);
    r.y = __shfl_xor(c.y, 32);
    r.z = __shfl_xor(c.z, 32);
    r.w = __shfl_xor(c.w, 32);
    return r;
}

__global__ __launch_bounds__(256) void cns_residuals_kernel(
    const float* __restrict__ vars,
    const float* __restrict__ s_dx, const float* __restrict__ s_dt,
    const float* __restrict__ s_eta, const float* __restrict__ s_zeta,
    float* __restrict__ out)
{
    const float dx = s_dx[0], dt = s_dt[0], eta = s_eta[0], zeta = s_zeta[0];
    const float bulk = zeta + eta * (1.0f / 3.0f);
    const float c1 = 2.0f * dx * dx;
    const float c2 = 2.0f * dt * dx;
    const float c3 = 4.0f * dt;
    const float c4 = 2.0f * dt;
    const float bc4 = bulk * c4;

    // persistent blocks, XCD-contiguous tile ranges
    const int i = blockIdx.x;                      // 1024 blocks
    const int lb = (i & 7) * 128 + (i >> 3);       // XCD k -> lb [k*128,(k+1)*128)
    const int tile0 = (lb * 7812) >> 10;
    const int tile1 = ((lb + 1) * 7812) >> 10;

    const int j = threadIdx.x & 31;                // y-group: outputs y=4j+1..4j+4
    const int g = threadIdx.x >> 5;                // 32-thread group 0..7
    const int h = g & 1;                           // half: row xp (even) / xp+1
    const int q = 4 * j;

    const float ssgn = h ? -1.0f : 1.0f;
    const float dts  = dt * ssgn;
    const float c2s  = c2 * ssgn;
    const float bc4s = bc4 * ssgn;

    const float mLo = (j == 0)  ? 0.0f : 1.0f;     // y' = -1 reads 0
    const float mHi = (j == 31) ? 0.0f : 1.0f;     // y' >= 128 reads 0

    const size_t plane = 16384;                    // 128*128
    const size_t cstr  = (size_t)64 * plane;
    const size_t oplane = 126 * 126;
    const size_t ocstr  = (size_t)62 * oplane;

    for (int tile = tile0; tile < tile1; ++tile) {
        int r = (tile << 3) | g;
        const int xp = r % 126; r /= 126;
        const int tp = r % 62;  const int b = r / 62;
        const int x = xp + 1, t = tp + 1;

        const float* Rch = vars + (size_t)b * 4 * cstr + (size_t)t * plane;
        const float* Uch = Rch + cstr;
        const float* Vch = Rch + 2 * cstr;
        const float* Pch = Rch + 3 * cstr;

        const int xe = x + 2 * h - 1;      // exclusive row: h0 -> x-1, h1 -> x+1
        const int xo = x + 4 * h - 2;      // U outer row:  h0 -> x-2, h1 -> x+2

        // ---- 9 aligned x-row loads ----
        const vf4 R_c = ld4(Rch + ((size_t)x  << 7) + q);
        const vf4 R_e = ld4(Rch + ((size_t)xe << 7) + q);
        const vf4 U_c = ld4(Uch + ((size_t)x  << 7) + q);
        const vf4 U_i = ld4(Uch + ((size_t)xe << 7) + q);
        vf4 U_o = {0.0f, 0.0f, 0.0f, 0.0f};
        if ((unsigned)xo < 128u) U_o = ld4(Uch + ((size_t)xo << 7) + q);
        const vf4 V_c = ld4(Vch + ((size_t)x  << 7) + q);
        const vf4 V_e = ld4(Vch + ((size_t)xe << 7) + q);
        const vf4 P_c = ld4(Pch + ((size_t)x  << 7) + q);
        const vf4 P_e = ld4(Pch + ((size_t)xe << 7) + q);

        // ---- 6 t+-1 center loads ----
        const float* rowR = Rch + ((size_t)x << 7) + q + 1;
        const vf4 rtp = ld4(rowR + plane),            rtm = ld4(rowR - plane);
        const vf4 utp = ld4(rowR + cstr + plane),     utm = ld4(rowR + cstr - plane);
        const vf4 vtp = ld4(rowR + 2 * cstr + plane), vtm = ld4(rowR + 2 * cstr - plane);

        // ---- half-swaps ----
        const vf4 Rcs = swap4(R_c);
        const vf4 Pcs = swap4(P_c);
        const vf4 Ucs = swap4(U_c);
        const vf4 Uis = swap4(U_i);
        const vf4 Vcs = swap4(V_c);

        // ---- windows ----
        const Win Rw  = mkwin(R_c, mHi);
        const Win Pw  = mkwin(P_c, mHi);
        const Win Uw0 = mkwin(U_c, mHi);
        const Win Vw0 = mkwin2(V_c, mLo, mHi);
        const Win Au  = mkwin(U_i, mHi);   // h0: row x-1 | h1: row x+2
        const Win Bu  = mkwin(Ucs, mHi);   // h0: row x+1 | h1: row x
        const Win Av  = mkwin(V_e, mHi);
        const Win Bv  = mkwin(Vcs, mHi);

        const vf4 rho = SH(Rw, 0);
        const vf4 u   = SH(Uw0, 0);
        const vf4 v   = SH(Vw0, 0);
        const vf4 uyp = SH(Uw0, 1), uym = SH(Uw0, -1);
        const vf4 vyp = SH(Vw0, 1), vym = SH(Vw0, -1);

        const vf4 au = SH(Au, 0), bu = SH(Bu, 0);
        const vf4 av = SH(Av, 0), bv = SH(Bv, 0);
        const vf4 sum_ux = au + bu;
        const vf4 sum_vx = av + bv;
        const vf4 rawDx_u = bu - au;                 // ssgn * Dx_u
        const vf4 rawDx_v = bv - av;                 // ssgn * Dx_v

        const vf4 rawDx_rho = ctrf(Rcs - R_e, mHi);  // ssgn * Dx_rho
        const vf4 rawDx_p   = ctrf(Pcs - P_e, mHi);  // ssgn * Dx_p
        const vf4 usum2     = ctrf(U_o + Uis, mHi);  // u(x+2)+u(x-2)

        const vf4 Dy_rho = SH(Rw, 1) - SH(Rw, -1);
        const vf4 Dy_p   = SH(Pw, 1) - SH(Pw, -1);
        const vf4 Dy_u   = uyp - uym;
        const vf4 Dy_v   = vyp - vym;

        const vf4 lap_u = sum_ux + uyp + uym - 4.0f * u;
        const vf4 lap_v = sum_vx + vyp + vym - 4.0f * v;

        const vf4 unsignedDiv = (usum2 - 2.0f * u)
                              + (SH(Vw0, 2) - 2.0f * v + SH(Vw0, -2));
        const vf4 signedDiv = (SH(Bv, 1) - SH(Bv, -1)) - (SH(Av, 1) - SH(Av, -1))
                            + (SH(Bu, 1) - SH(Bu, -1)) - (SH(Au, 1) - SH(Au, -1));

        const vf4 Dt_rho = rtp - rtm;
        const vf4 Dt_u = utp - utm, Dt_v = vtp - vtm;

        const vf4 mass = Dt_rho * dx
                       + (rho * rawDx_u + u * rawDx_rho) * dts
                       + (rho * Dy_v + v * Dy_rho) * dt;

        const vf4 mom = rho * (Dt_u + Dt_v) * c1
                      + (u * (rawDx_u + rawDx_v) + rawDx_p) * c2s
                      + (v * (Dy_u + Dy_v) + Dy_p) * c2
                      - eta * (lap_u + lap_v) * c3
                      - bc4 * unsignedDiv - bc4s * signedDiv;

        float* o1 = out + (size_t)b * 2 * ocstr + (size_t)tp * oplane
                  + (size_t)xp * 126 + q;
        float* o2 = o1 + ocstr;
        if (j < 31) {
            __builtin_nontemporal_store(mass, reinterpret_cast<vf4u*>(o1));
            __builtin_nontemporal_store(mom,  reinterpret_cast<vf4u*>(o2));
        } else {  // outputs y=127,128 out of range; store only 2
            __builtin_nontemporal_store(mass[0], o1);
            __builtin_nontemporal_store(mass[1], o1 + 1);
            __builtin_nontemporal_store(mom[0],  o2);
            __builtin_nontemporal_store(mom[1],  o2 + 1);
        }
    }
}

extern "C" void kernel_launch(void* const* d_in, const int* in_sizes, int n_in,
                              void* d_out, int out_size, void* d_ws, size_t ws_size,
                              hipStream_t stream) {
    const float* vars   = (const float*)d_in[0];
    const float* s_dx   = (const float*)d_in[1];
    const float* s_dt   = (const float*)d_in[2];
    const float* s_eta  = (const float*)d_in[3];
    const float* s_zeta = (const float*)d_in[4];
    float* out = (float*)d_out;

    const int grid = 1024;  // persistent: 4 blocks/CU, loop over 7812 tiles
    hipLaunchKernelGGL(cns_residuals_kernel, dim3(grid), dim3(256), 0, stream,
                       vars, s_dx, s_dt, s_eta, s_zeta, out);
}

// Round 11
// 41.096 us; speedup vs baseline: 1.1788x; 1.1788x over previous
//
#include <hip/hip_runtime.h>

// CNS residuals: vars (B=8, C=4, T=64, X=128, Y=128) f32
// out (B=8, 2, 62, 126, 126) f32: [mass, mom_x+mom_y] inner region.
// R11 = R9 + 2 independent tiles per block (ILP/MLP doubling).
// Block 256 thr handles tiles 2lb, 2lb+1 (xp-adjacent): issue all of A's
// 15 loads, then all of B's, then compute+store A (B's loads in flight),
// then compute+store B. Dispatcher-ordered blocks keep the rolling tp
// window (R10 lesson: concurrent tp spread must stay small).
// Half-wave x-row sharing + aligned x-loads + XCD swizzle + NT stores kept.

typedef float vf4 __attribute__((ext_vector_type(4)));
typedef float vf4u __attribute__((ext_vector_type(4), aligned(4)));

__device__ __forceinline__ vf4 ld4(const float* p) {
    return *reinterpret_cast<const vf4u*>(p);
}

struct Win { vf4 lo, hi; };
// window covers y' = 4j-1 .. 4j+6; output elem e at shift s -> index 2+e+s
#define SH(w, s) __builtin_shufflevector((w).lo, (w).hi, 2 + (s), 3 + (s), 4 + (s), 5 + (s))

__device__ __forceinline__ Win mkwin(vf4 c, float mHi) {
    const float dn0 = __shfl_down(c.x, 1) * mHi;
    const float dn1 = __shfl_down(c.y, 1) * mHi;
    Win w;
    w.lo = (vf4){0.0f, c.x, c.y, c.z};
    w.hi = (vf4){c.w, dn0, dn1, 0.0f};
    return w;
}
__device__ __forceinline__ Win mkwin2(vf4 c, float mLo, float mHi) {
    const float up3 = __shfl_up(c.w, 1) * mLo;
    const float dn0 = __shfl_down(c.x, 1) * mHi;
    const float dn1 = __shfl_down(c.y, 1) * mHi;
    const float dn2 = __shfl_down(c.z, 1) * mHi;
    Win w;
    w.lo = (vf4){up3, c.x, c.y, c.z};
    w.hi = (vf4){c.w, dn0, dn1, dn2};
    return w;
}
__device__ __forceinline__ vf4 ctrf(vf4 c, float mHi) {
    const float dn0 = __shfl_down(c.x, 1) * mHi;
    return (vf4){c.y, c.z, c.w, dn0};
}
__device__ __forceinline__ vf4 swap4(vf4 c) {
    vf4 r;
    r.x = __shfl_xor(c.x, 32);
    r.y = __shfl_xor(c.y, 32);
    r.z = __shfl_xor(c.z, 32);
    r.w = __shfl_xor(c.w, 32);
    return r;
}

struct Loads {
    vf4 R_c, R_e, U_c, U_i, U_o, V_c, V_e, P_c, P_e;
    vf4 rtp, rtm, utp, utm, vtp, vtm;
    int xp, tp, b;
};

__device__ __forceinline__ Loads loadTile(int tile, int g, int h, int q,
                                          const float* __restrict__ vars) {
    Loads L;
    int r = (tile << 3) | g;
    L.xp = r % 126; r /= 126;
    L.tp = r % 62;  L.b = r / 62;
    const int x = L.xp + 1, t = L.tp + 1;

    const size_t plane = 16384;
    const size_t cstr  = (size_t)64 * plane;
    const float* Rch = vars + (size_t)L.b * 4 * cstr + (size_t)t * plane;
    const float* Uch = Rch + cstr;
    const float* Vch = Rch + 2 * cstr;
    const float* Pch = Rch + 3 * cstr;

    const int xe = x + 2 * h - 1;      // h0 -> x-1, h1 -> x+1
    const int xo = x + 4 * h - 2;      // h0 -> x-2, h1 -> x+2

    L.R_c = ld4(Rch + ((size_t)x  << 7) + q);
    L.R_e = ld4(Rch + ((size_t)xe << 7) + q);
    L.U_c = ld4(Uch + ((size_t)x  << 7) + q);
    L.U_i = ld4(Uch + ((size_t)xe << 7) + q);
    L.U_o = (vf4){0.0f, 0.0f, 0.0f, 0.0f};
    if ((unsigned)xo < 128u) L.U_o = ld4(Uch + ((size_t)xo << 7) + q);
    L.V_c = ld4(Vch + ((size_t)x  << 7) + q);
    L.V_e = ld4(Vch + ((size_t)xe << 7) + q);
    L.P_c = ld4(Pch + ((size_t)x  << 7) + q);
    L.P_e = ld4(Pch + ((size_t)xe << 7) + q);

    const float* rowR = Rch + ((size_t)x << 7) + q + 1;
    L.rtp = ld4(rowR + plane);            L.rtm = ld4(rowR - plane);
    L.utp = ld4(rowR + cstr + plane);     L.utm = ld4(rowR + cstr - plane);
    L.vtp = ld4(rowR + 2 * cstr + plane); L.vtm = ld4(rowR + 2 * cstr - plane);
    return L;
}

__device__ __forceinline__ void computeStore(
    const Loads& L, int j, int q,
    float mLo, float mHi,
    float dx, float dt, float dts, float c1, float c2, float c2s,
    float c3, float eta, float bc4, float bc4s,
    float* __restrict__ out)
{
    // half-swaps
    const vf4 Rcs = swap4(L.R_c);
    const vf4 Pcs = swap4(L.P_c);
    const vf4 Ucs = swap4(L.U_c);
    const vf4 Uis = swap4(L.U_i);
    const vf4 Vcs = swap4(L.V_c);

    // windows
    const Win Rw  = mkwin(L.R_c, mHi);
    const Win Pw  = mkwin(L.P_c, mHi);
    const Win Uw0 = mkwin(L.U_c, mHi);
    const Win Vw0 = mkwin2(L.V_c, mLo, mHi);
    const Win Au  = mkwin(L.U_i, mHi);
    const Win Bu  = mkwin(Ucs, mHi);
    const Win Av  = mkwin(L.V_e, mHi);
    const Win Bv  = mkwin(Vcs, mHi);

    const vf4 rho = SH(Rw, 0);
    const vf4 u   = SH(Uw0, 0);
    const vf4 v   = SH(Vw0, 0);
    const vf4 uyp = SH(Uw0, 1), uym = SH(Uw0, -1);
    const vf4 vyp = SH(Vw0, 1), vym = SH(Vw0, -1);

    const vf4 au = SH(Au, 0), bu = SH(Bu, 0);
    const vf4 av = SH(Av, 0), bv = SH(Bv, 0);
    const vf4 sum_ux = au + bu;
    const vf4 sum_vx = av + bv;
    const vf4 rawDx_u = bu - au;                    // ssgn * Dx_u
    const vf4 rawDx_v = bv - av;                    // ssgn * Dx_v

    const vf4 rawDx_rho = ctrf(Rcs - L.R_e, mHi);   // ssgn * Dx_rho
    const vf4 rawDx_p   = ctrf(Pcs - L.P_e, mHi);   // ssgn * Dx_p
    const vf4 usum2     = ctrf(L.U_o + Uis, mHi);   // u(x+2)+u(x-2)

    const vf4 Dy_rho = SH(Rw, 1) - SH(Rw, -1);
    const vf4 Dy_p   = SH(Pw, 1) - SH(Pw, -1);
    const vf4 Dy_u   = uyp - uym;
    const vf4 Dy_v   = vyp - vym;

    const vf4 lap_u = sum_ux + uyp + uym - 4.0f * u;
    const vf4 lap_v = sum_vx + vyp + vym - 4.0f * v;

    const vf4 unsignedDiv = (usum2 - 2.0f * u)
                          + (SH(Vw0, 2) - 2.0f * v + SH(Vw0, -2));
    const vf4 signedDiv = (SH(Bv, 1) - SH(Bv, -1)) - (SH(Av, 1) - SH(Av, -1))
                        + (SH(Bu, 1) - SH(Bu, -1)) - (SH(Au, 1) - SH(Au, -1));

    const vf4 Dt_rho = L.rtp - L.rtm;
    const vf4 Dt_u = L.utp - L.utm, Dt_v = L.vtp - L.vtm;

    const vf4 mass = Dt_rho * dx
                   + (rho * rawDx_u + u * rawDx_rho) * dts
                   + (rho * Dy_v + v * Dy_rho) * dt;

    const vf4 mom = rho * (Dt_u + Dt_v) * c1
                  + (u * (rawDx_u + rawDx_v) + rawDx_p) * c2s
                  + (v * (Dy_u + Dy_v) + Dy_p) * c2
                  - eta * (lap_u + lap_v) * c3
                  - bc4 * unsignedDiv - bc4s * signedDiv;

    const size_t oplane = 126 * 126;
    const size_t ocstr  = (size_t)62 * oplane;
    float* o1 = out + (size_t)L.b * 2 * ocstr + (size_t)L.tp * oplane
              + (size_t)L.xp * 126 + q;
    float* o2 = o1 + ocstr;
    if (j < 31) {
        __builtin_nontemporal_store(mass, reinterpret_cast<vf4u*>(o1));
        __builtin_nontemporal_store(mom,  reinterpret_cast<vf4u*>(o2));
    } else {  // outputs y=127,128 out of range; store only 2
        __builtin_nontemporal_store(mass[0], o1);
        __builtin_nontemporal_store(mass[1], o1 + 1);
        __builtin_nontemporal_store(mom[0],  o2);
        __builtin_nontemporal_store(mom[1],  o2 + 1);
    }
}

__global__ __launch_bounds__(256) void cns_residuals_kernel(
    const float* __restrict__ vars,
    const float* __restrict__ s_dx, const float* __restrict__ s_dt,
    const float* __restrict__ s_eta, const float* __restrict__ s_zeta,
    float* __restrict__ out)
{
    const float dx = s_dx[0], dt = s_dt[0], eta = s_eta[0], zeta = s_zeta[0];
    const float bulk = zeta + eta * (1.0f / 3.0f);
    const float c1 = 2.0f * dx * dx;
    const float c2 = 2.0f * dt * dx;
    const float c3 = 4.0f * dt;
    const float c4 = 2.0f * dt;
    const float bc4 = bulk * c4;

    // bijective XCD-chunked swizzle: nwg = 3906 = 8*488 + 2
    const int i = blockIdx.x;
    const int xcd = i & 7;
    const int slot = i >> 3;
    const int lb = ((xcd < 2) ? xcd * 489 : 978 + (xcd - 2) * 488) + slot;

    const int j = threadIdx.x & 31;         // y-group: outputs y = 4j+1..4j+4
    const int g = threadIdx.x >> 5;         // 32-thread group 0..7
    const int h = g & 1;                    // half: even row / odd row
    const int q = 4 * j;

    const float ssgn = h ? -1.0f : 1.0f;
    const float dts  = dt * ssgn;
    const float c2s  = c2 * ssgn;
    const float bc4s = bc4 * ssgn;

    const float mLo = (j == 0)  ? 0.0f : 1.0f;   // y' = -1 reads 0
    const float mHi = (j == 31) ? 0.0f : 1.0f;   // y' >= 128 reads 0

    // issue both tiles' loads back-to-back (2x memory-level parallelism),
    // then compute/store each.
    const Loads LA = loadTile(2 * lb,     g, h, q, vars);
    const Loads LB = loadTile(2 * lb + 1, g, h, q, vars);

    computeStore(LA, j, q, mLo, mHi, dx, dt, dts, c1, c2, c2s, c3, eta,
                 bc4, bc4s, out);
    computeStore(LB, j, q, mLo, mHi, dx, dt, dts, c1, c2, c2s, c3, eta,
                 bc4, bc4s, out);
}

extern "C" void kernel_launch(void* const* d_in, const int* in_sizes, int n_in,
                              void* d_out, int out_size, void* d_ws, size_t ws_size,
                              hipStream_t stream) {
    const float* vars   = (const float*)d_in[0];
    const float* s_dx   = (const float*)d_in[1];
    const float* s_dt   = (const float*)d_in[2];
    const float* s_eta  = (const float*)d_in[3];
    const float* s_zeta = (const float*)d_in[4];
    float* out = (float*)d_out;

    const int grid = 3906;  // 2 tiles per block; 3906*2*8*32 = 2M lanes' work
    hipLaunchKernelGGL(cns_residuals_kernel, dim3(grid), dim3(256), 0, stream,
                       vars, s_dx, s_dt, s_eta, s_zeta, out);
}

// Round 12
// 39.565 us; speedup vs baseline: 1.2244x; 1.0387x over previous
//
#include <hip/hip_runtime.h>

// CNS residuals: vars (B=8, C=4, T=64, X=128, Y=128) f32
// out (B=8, 2, 62, 126, 126) f32: [mass, mom_x+mom_y] inner region.
// R12 = R9 + 512-thread blocks (8 waves/block; 16 consecutive xp rows per
// block -> x-halo reuse moves L2->L1, coarser residency quanta) + ALL loads
// 16B-aligned (t+-1 center loads now aligned chunk + ctrf shuffle; was the
// last misaligned access). Half-wave x-row sharing (shfl_xor 32), XCD
// swizzle, NT stores kept. 15 loads/thread, VGPR ~64.

typedef float vf4 __attribute__((ext_vector_type(4)));
typedef float vf4u __attribute__((ext_vector_type(4), aligned(4)));

__device__ __forceinline__ vf4 ld4(const float* p) {
    return *reinterpret_cast<const vf4u*>(p);
}

struct Win { vf4 lo, hi; };
// window covers y' = 4j-1 .. 4j+6; output elem e at shift s -> index 2+e+s
#define SH(w, s) __builtin_shufflevector((w).lo, (w).hi, 2 + (s), 3 + (s), 4 + (s), 5 + (s))

__device__ __forceinline__ Win mkwin(vf4 c, float mHi) {
    const float dn0 = __shfl_down(c.x, 1) * mHi;
    const float dn1 = __shfl_down(c.y, 1) * mHi;
    Win w;
    w.lo = (vf4){0.0f, c.x, c.y, c.z};
    w.hi = (vf4){c.w, dn0, dn1, 0.0f};
    return w;
}
__device__ __forceinline__ Win mkwin2(vf4 c, float mLo, float mHi) {
    const float up3 = __shfl_up(c.w, 1) * mLo;
    const float dn0 = __shfl_down(c.x, 1) * mHi;
    const float dn1 = __shfl_down(c.y, 1) * mHi;
    const float dn2 = __shfl_down(c.z, 1) * mHi;
    Win w;
    w.lo = (vf4){up3, c.x, c.y, c.z};
    w.hi = (vf4){c.w, dn0, dn1, dn2};
    return w;
}
// center values y = 4j+1..4j+4 from an aligned chunk
__device__ __forceinline__ vf4 ctrf(vf4 c, float mHi) {
    const float dn0 = __shfl_down(c.x, 1) * mHi;
    return (vf4){c.y, c.z, c.w, dn0};
}
__device__ __forceinline__ vf4 swap4(vf4 c) {
    vf4 r;
    r.x = __shfl_xor(c.x, 32);
    r.y = __shfl_xor(c.y, 32);
    r.z = __shfl_xor(c.z, 32);
    r.w = __shfl_xor(c.w, 32);
    return r;
}

__global__ __launch_bounds__(512) void cns_residuals_kernel(
    const float* __restrict__ vars,
    const float* __restrict__ s_dx, const float* __restrict__ s_dt,
    const float* __restrict__ s_eta, const float* __restrict__ s_zeta,
    float* __restrict__ out)
{
    const float dx = s_dx[0], dt = s_dt[0], eta = s_eta[0], zeta = s_zeta[0];
    const float bulk = zeta + eta * (1.0f / 3.0f);
    const float c1 = 2.0f * dx * dx;
    const float c2 = 2.0f * dt * dx;
    const float c3 = 4.0f * dt;
    const float c4 = 2.0f * dt;
    const float bc4 = bulk * c4;

    // bijective XCD-chunked swizzle: nwg = 3906 = 8*488 + 2
    const int i = blockIdx.x;
    const int xcd = i & 7;
    const int slot = i >> 3;
    const int lb = ((xcd < 2) ? xcd * 489 : 978 + (xcd - 2) * 488) + slot;

    const int tid = lb * 512 + threadIdx.x;
    const int j = tid & 31;            // y-group: outputs y = 4j+1 .. 4j+4
    int r = tid >> 5;
    const int xp = r % 126; r /= 126;
    const int tp = r % 62;  const int b = r / 62;
    const int x = xp + 1, t = tp + 1;
    const int q = 4 * j;
    const int h = (threadIdx.x >> 5) & 1;   // half: even row / odd row

    // per-half sign for x-differences
    const float ssgn = h ? -1.0f : 1.0f;
    const float dts  = dt * ssgn;
    const float c2s  = c2 * ssgn;
    const float bc4s = bc4 * ssgn;

    const size_t plane = 16384;                 // 128*128
    const size_t cstr  = (size_t)64 * plane;

    const float* Rch = vars + (size_t)b * 4 * cstr + (size_t)t * plane;
    const float* Uch = Rch + cstr;
    const float* Vch = Rch + 2 * cstr;
    const float* Pch = Rch + 3 * cstr;

    const int xe = x + 2 * h - 1;      // exclusive row: h0 -> x-1, h1 -> x+1
    const int xo = x + 4 * h - 2;      // U outer row:  h0 -> x-2, h1 -> x+2

    // ---- 9 aligned x-row loads ----
    const vf4 R_c = ld4(Rch + ((size_t)x  << 7) + q);
    const vf4 R_e = ld4(Rch + ((size_t)xe << 7) + q);
    const vf4 U_c = ld4(Uch + ((size_t)x  << 7) + q);
    const vf4 U_i = ld4(Uch + ((size_t)xe << 7) + q);
    vf4 U_o = {0.0f, 0.0f, 0.0f, 0.0f};
    if ((unsigned)xo < 128u) U_o = ld4(Uch + ((size_t)xo << 7) + q);
    const vf4 V_c = ld4(Vch + ((size_t)x  << 7) + q);
    const vf4 V_e = ld4(Vch + ((size_t)xe << 7) + q);
    const vf4 P_c = ld4(Pch + ((size_t)x  << 7) + q);
    const vf4 P_e = ld4(Pch + ((size_t)xe << 7) + q);

    // ---- 6 t+-1 loads, now aligned (center values via ctrf below) ----
    const float* rowA = Rch + ((size_t)x << 7) + q;
    const vf4 rtpA = ld4(rowA + plane),            rtmA = ld4(rowA - plane);
    const vf4 utpA = ld4(rowA + cstr + plane),     utmA = ld4(rowA + cstr - plane);
    const vf4 vtpA = ld4(rowA + 2 * cstr + plane), vtmA = ld4(rowA + 2 * cstr - plane);

    const float mLo = (j == 0)  ? 0.0f : 1.0f;   // y' = -1 reads 0
    const float mHi = (j == 31) ? 0.0f : 1.0f;   // y' >= 128 reads 0

    // ---- half-swaps (5 x 4 shfl_xor) ----
    const vf4 Rcs = swap4(R_c);
    const vf4 Pcs = swap4(P_c);
    const vf4 Ucs = swap4(U_c);
    const vf4 Uis = swap4(U_i);
    const vf4 Vcs = swap4(V_c);

    // ---- windows ----
    const Win Rw  = mkwin(R_c, mHi);
    const Win Pw  = mkwin(P_c, mHi);
    const Win Uw0 = mkwin(U_c, mHi);
    const Win Vw0 = mkwin2(V_c, mLo, mHi);
    const Win Au  = mkwin(U_i, mHi);   // h0: row x-1 | h1: row x+2
    const Win Bu  = mkwin(Ucs, mHi);   // h0: row x+1 | h1: row x
    const Win Av  = mkwin(V_e, mHi);
    const Win Bv  = mkwin(Vcs, mHi);

    // t+-1 center values y = 4j+1..4j+4
    const vf4 rtp = ctrf(rtpA, mHi), rtm = ctrf(rtmA, mHi);
    const vf4 utp = ctrf(utpA, mHi), utm = ctrf(utmA, mHi);
    const vf4 vtp = ctrf(vtpA, mHi), vtm = ctrf(vtmA, mHi);

    const vf4 rho = SH(Rw, 0);
    const vf4 u   = SH(Uw0, 0);
    const vf4 v   = SH(Vw0, 0);
    const vf4 uyp = SH(Uw0, 1), uym = SH(Uw0, -1);
    const vf4 vyp = SH(Vw0, 1), vym = SH(Vw0, -1);

    // x-neighbor centers: B = (h? xm : xp), A = (h? xp : xm)
    const vf4 au = SH(Au, 0), bu = SH(Bu, 0);
    const vf4 av = SH(Av, 0), bv = SH(Bv, 0);
    const vf4 sum_ux = au + bu;                  // uxp + uxm (sign-free)
    const vf4 sum_vx = av + bv;                  // vxp + vxm
    const vf4 rawDx_u = bu - au;                 // ssgn * Dx_u
    const vf4 rawDx_v = bv - av;                 // ssgn * Dx_v

    const vf4 rawDx_rho = ctrf(Rcs - R_e, mHi);  // ssgn * Dx_rho
    const vf4 rawDx_p   = ctrf(Pcs - P_e, mHi);  // ssgn * Dx_p
    const vf4 usum2     = ctrf(U_o + Uis, mHi);  // u(x+2)+u(x-2)

    const vf4 Dy_rho = SH(Rw, 1) - SH(Rw, -1);
    const vf4 Dy_p   = SH(Pw, 1) - SH(Pw, -1);
    const vf4 Dy_u   = uyp - uym;
    const vf4 Dy_v   = vyp - vym;

    const vf4 lap_u = sum_ux + uyp + uym - 4.0f * u;
    const vf4 lap_v = sum_vx + vyp + vym - 4.0f * v;

    const vf4 unsignedDiv = (usum2 - 2.0f * u)
                          + (SH(Vw0, 2) - 2.0f * v + SH(Vw0, -2));
    const vf4 signedDiv = (SH(Bv, 1) - SH(Bv, -1)) - (SH(Av, 1) - SH(Av, -1))
                        + (SH(Bu, 1) - SH(Bu, -1)) - (SH(Au, 1) - SH(Au, -1));

    const vf4 Dt_rho = rtp - rtm;
    const vf4 Dt_u = utp - utm, Dt_v = vtp - vtm;

    const vf4 mass = Dt_rho * dx
                   + (rho * rawDx_u + u * rawDx_rho) * dts
                   + (rho * Dy_v + v * Dy_rho) * dt;

    const vf4 mom = rho * (Dt_u + Dt_v) * c1
                  + (u * (rawDx_u + rawDx_v) + rawDx_p) * c2s
                  + (v * (Dy_u + Dy_v) + Dy_p) * c2
                  - eta * (lap_u + lap_v) * c3
                  - bc4 * unsignedDiv - bc4s * signedDiv;

    const size_t oplane = 126 * 126;
    const size_t ocstr  = (size_t)62 * oplane;
    float* o1 = out + (size_t)b * 2 * ocstr + (size_t)tp * oplane
              + (size_t)xp * 126 + q;
    float* o2 = o1 + ocstr;
    if (j < 31) {
        __builtin_nontemporal_store(mass, reinterpret_cast<vf4u*>(o1));
        __builtin_nontemporal_store(mom,  reinterpret_cast<vf4u*>(o2));
    } else {  // outputs y=127,128 out of range; store only 2
        __builtin_nontemporal_store(mass[0], o1);
        __builtin_nontemporal_store(mass[1], o1 + 1);
        __builtin_nontemporal_store(mom[0],  o2);
        __builtin_nontemporal_store(mom[1],  o2 + 1);
    }
}

extern "C" void kernel_launch(void* const* d_in, const int* in_sizes, int n_in,
                              void* d_out, int out_size, void* d_ws, size_t ws_size,
                              hipStream_t stream) {
    const float* vars   = (const float*)d_in[0];
    const float* s_dx   = (const float*)d_in[1];
    const float* s_dt   = (const float*)d_in[2];
    const float* s_eta  = (const float*)d_in[3];
    const float* s_zeta = (const float*)d_in[4];
    float* out = (float*)d_out;

    const int grid = 3906;  // 8*62*126*32 threads / 512
    hipLaunchKernelGGL(cns_residuals_kernel, dim3(grid), dim3(512), 0, stream,
                       vars, s_dx, s_dt, s_eta, s_zeta, out);
}

// Round 13
// 36.434 us; speedup vs baseline: 1.3296x; 1.0859x over previous
//
#include <hip/hip_runtime.h>

// CNS residuals: vars (B=8, C=4, T=64, X=128, Y=128) f32
// out (B=8, 2, 62, 126, 126) f32: [mass, mom_x+mom_y] inner region.
// R13 = exact revert to R9 (best: 36.1 us). R9 = R5 + half-wave x-row
// sharing. Wave halves handle rows x0 / x0+1; each lane loads own-center
// rows (R,U,V,P), exclusive row x+2h-1, U-outer x+4h-2; missing x-neighbor
// rows come via __shfl_xor(.,32). x-diff signs folded into coefficients.
// 15 aligned loads/thread. XCD-chunked swizzle + NT stores.
// Structure search exhausted: R4/R8/R10/R11/R12 (x-pair, vf2, persistent,
// 2-tile ILP, 512-thr) all regressed; latency floor ~1.6x HBM bound.

typedef float vf4 __attribute__((ext_vector_type(4)));
typedef float vf4u __attribute__((ext_vector_type(4), aligned(4)));

__device__ __forceinline__ vf4 ld4(const float* p) {
    return *reinterpret_cast<const vf4u*>(p);
}

struct Win { vf4 lo, hi; };
// window covers y' = 4j-1 .. 4j+6; output elem e at shift s -> index 2+e+s
#define SH(w, s) __builtin_shufflevector((w).lo, (w).hi, 2 + (s), 3 + (s), 4 + (s), 5 + (s))

__device__ __forceinline__ Win mkwin(vf4 c, float mHi) {
    const float dn0 = __shfl_down(c.x, 1) * mHi;
    const float dn1 = __shfl_down(c.y, 1) * mHi;
    Win w;
    w.lo = (vf4){0.0f, c.x, c.y, c.z};
    w.hi = (vf4){c.w, dn0, dn1, 0.0f};
    return w;
}
__device__ __forceinline__ Win mkwin2(vf4 c, float mLo, float mHi) {
    const float up3 = __shfl_up(c.w, 1) * mLo;
    const float dn0 = __shfl_down(c.x, 1) * mHi;
    const float dn1 = __shfl_down(c.y, 1) * mHi;
    const float dn2 = __shfl_down(c.z, 1) * mHi;
    Win w;
    w.lo = (vf4){up3, c.x, c.y, c.z};
    w.hi = (vf4){c.w, dn0, dn1, dn2};
    return w;
}
// center values y = 4j+1..4j+4 from an aligned chunk
__device__ __forceinline__ vf4 ctrf(vf4 c, float mHi) {
    const float dn0 = __shfl_down(c.x, 1) * mHi;
    return (vf4){c.y, c.z, c.w, dn0};
}
// other half's same-j value
__device__ __forceinline__ vf4 swap4(vf4 c) {
    vf4 r;
    r.x = __shfl_xor(c.x, 32);
    r.y = __shfl_xor(c.y, 32);
    r.z = __shfl_xor(c.z, 32);
    r.w = __shfl_xor(c.w, 32);
    return r;
}

__global__ __launch_bounds__(256) void cns_residuals_kernel(
    const float* __restrict__ vars,
    const float* __restrict__ s_dx, const float* __restrict__ s_dt,
    const float* __restrict__ s_eta, const float* __restrict__ s_zeta,
    float* __restrict__ out)
{
    const float dx = s_dx[0], dt = s_dt[0], eta = s_eta[0], zeta = s_zeta[0];
    const float bulk = zeta + eta * (1.0f / 3.0f);
    const float c1 = 2.0f * dx * dx;
    const float c2 = 2.0f * dt * dx;
    const float c3 = 4.0f * dt;
    const float c4 = 2.0f * dt;
    const float bc4 = bulk * c4;

    // XCD-chunked bijective swizzle: nwg = 7812 = 8*976 + 4
    const int i = blockIdx.x;
    const int xcd = i & 7;
    const int slot = i >> 3;
    const int lb = ((xcd < 4) ? xcd * 977 : 3908 + (xcd - 4) * 976) + slot;

    const int tid = lb * 256 + threadIdx.x;
    const int j = tid & 31;            // y-group: outputs y = 4j+1 .. 4j+4
    int r = tid >> 5;
    const int xp = r % 126; r /= 126;
    const int tp = r % 62;  const int b = r / 62;
    const int x = xp + 1, t = tp + 1;
    const int q = 4 * j;
    const int h = (threadIdx.x >> 5) & 1;   // half: row x0 (0) / x0+1 (1)

    // per-half sign for x-differences
    const float ssgn = h ? -1.0f : 1.0f;
    const float dts  = dt * ssgn;
    const float c2s  = c2 * ssgn;
    const float bc4s = bc4 * ssgn;

    const size_t plane = 16384;                 // 128*128
    const size_t cstr  = (size_t)64 * plane;

    const float* Rch = vars + (size_t)b * 4 * cstr + (size_t)t * plane;
    const float* Uch = Rch + cstr;
    const float* Vch = Rch + 2 * cstr;
    const float* Pch = Rch + 3 * cstr;

    const int xe = x + 2 * h - 1;      // exclusive row: h0 -> x-1, h1 -> x+1
    const int xo = x + 4 * h - 2;      // U outer row:  h0 -> x-2, h1 -> x+2

    // ---- 9 aligned x-row loads ----
    const vf4 R_c = ld4(Rch + ((size_t)x  << 7) + q);
    const vf4 R_e = ld4(Rch + ((size_t)xe << 7) + q);
    const vf4 U_c = ld4(Uch + ((size_t)x  << 7) + q);
    const vf4 U_i = ld4(Uch + ((size_t)xe << 7) + q);
    vf4 U_o = {0.0f, 0.0f, 0.0f, 0.0f};
    if ((unsigned)xo < 128u) U_o = ld4(Uch + ((size_t)xo << 7) + q);
    const vf4 V_c = ld4(Vch + ((size_t)x  << 7) + q);
    const vf4 V_e = ld4(Vch + ((size_t)xe << 7) + q);
    const vf4 P_c = ld4(Pch + ((size_t)x  << 7) + q);
    const vf4 P_e = ld4(Pch + ((size_t)xe << 7) + q);

    // ---- 6 t+-1 center loads (misaligned, as in R5) ----
    const float* rowR = Rch + ((size_t)x << 7) + q + 1;
    const vf4 rtp = ld4(rowR + plane),            rtm = ld4(rowR - plane);
    const vf4 utp = ld4(rowR + cstr + plane),     utm = ld4(rowR + cstr - plane);
    const vf4 vtp = ld4(rowR + 2 * cstr + plane), vtm = ld4(rowR + 2 * cstr - plane);

    const float mLo = (j == 0)  ? 0.0f : 1.0f;   // y' = -1 reads 0
    const float mHi = (j == 31) ? 0.0f : 1.0f;   // y' >= 128 reads 0

    // ---- half-swaps (5 x 4 shfl_xor) ----
    const vf4 Rcs = swap4(R_c);
    const vf4 Pcs = swap4(P_c);
    const vf4 Ucs = swap4(U_c);
    const vf4 Uis = swap4(U_i);
    const vf4 Vcs = swap4(V_c);

    // ---- windows ----
    const Win Rw  = mkwin(R_c, mHi);
    const Win Pw  = mkwin(P_c, mHi);
    const Win Uw0 = mkwin(U_c, mHi);
    const Win Vw0 = mkwin2(V_c, mLo, mHi);
    const Win Au  = mkwin(U_i, mHi);   // h0: row x-1 | h1: row x+2
    const Win Bu  = mkwin(Ucs, mHi);   // h0: row x+1 | h1: row x
    const Win Av  = mkwin(V_e, mHi);
    const Win Bv  = mkwin(Vcs, mHi);

    const vf4 rho = SH(Rw, 0);
    const vf4 u   = SH(Uw0, 0);
    const vf4 v   = SH(Vw0, 0);
    const vf4 uyp = SH(Uw0, 1), uym = SH(Uw0, -1);
    const vf4 vyp = SH(Vw0, 1), vym = SH(Vw0, -1);

    // x-neighbor centers: B = (h? xm : xp), A = (h? xp : xm)
    const vf4 au = SH(Au, 0), bu = SH(Bu, 0);
    const vf4 av = SH(Av, 0), bv = SH(Bv, 0);
    const vf4 sum_ux = au + bu;                  // uxp + uxm (sign-free)
    const vf4 sum_vx = av + bv;                  // vxp + vxm
    const vf4 rawDx_u = bu - au;                 // ssgn * Dx_u
    const vf4 rawDx_v = bv - av;                 // ssgn * Dx_v

    const vf4 rawDx_rho = ctrf(Rcs - R_e, mHi);  // ssgn * Dx_rho
    const vf4 rawDx_p   = ctrf(Pcs - P_e, mHi);  // ssgn * Dx_p
    const vf4 usum2     = ctrf(U_o + Uis, mHi);  // u(x+2)+u(x-2)

    const vf4 Dy_rho = SH(Rw, 1) - SH(Rw, -1);
    const vf4 Dy_p   = SH(Pw, 1) - SH(Pw, -1);
    const vf4 Dy_u   = uyp - uym;
    const vf4 Dy_v   = vyp - vym;

    const vf4 lap_u = sum_ux + uyp + uym - 4.0f * u;
    const vf4 lap_v = sum_vx + vyp + vym - 4.0f * v;

    // div derivatives: sign-free and signed parts
    const vf4 unsignedDiv = (usum2 - 2.0f * u)
                          + (SH(Vw0, 2) - 2.0f * v + SH(Vw0, -2));
    const vf4 signedDiv = (SH(Bv, 1) - SH(Bv, -1)) - (SH(Av, 1) - SH(Av, -1))
                        + (SH(Bu, 1) - SH(Bu, -1)) - (SH(Au, 1) - SH(Au, -1));

    const vf4 Dt_rho = rtp - rtm;
    const vf4 Dt_u = utp - utm, Dt_v = vtp - vtm;

    const vf4 mass = Dt_rho * dx
                   + (rho * rawDx_u + u * rawDx_rho) * dts
                   + (rho * Dy_v + v * Dy_rho) * dt;

    const vf4 mom = rho * (Dt_u + Dt_v) * c1
                  + (u * (rawDx_u + rawDx_v) + rawDx_p) * c2s
                  + (v * (Dy_u + Dy_v) + Dy_p) * c2
                  - eta * (lap_u + lap_v) * c3
                  - bc4 * unsignedDiv - bc4s * signedDiv;

    const size_t oplane = 126 * 126;
    const size_t ocstr  = (size_t)62 * oplane;
    float* o1 = out + (size_t)b * 2 * ocstr + (size_t)tp * oplane
              + (size_t)xp * 126 + q;
    float* o2 = o1 + ocstr;
    if (j < 31) {
        __builtin_nontemporal_store(mass, reinterpret_cast<vf4u*>(o1));
        __builtin_nontemporal_store(mom,  reinterpret_cast<vf4u*>(o2));
    } else {  // outputs y=127,128 out of range; store only 2
        __builtin_nontemporal_store(mass[0], o1);
        __builtin_nontemporal_store(mass[1], o1 + 1);
        __builtin_nontemporal_store(mom[0],  o2);
        __builtin_nontemporal_store(mom[1],  o2 + 1);
    }
}

extern "C" void kernel_launch(void* const* d_in, const int* in_sizes, int n_in,
                              void* d_out, int out_size, void* d_ws, size_t ws_size,
                              hipStream_t stream) {
    const float* vars   = (const float*)d_in[0];
    const float* s_dx   = (const float*)d_in[1];
    const float* s_dt   = (const float*)d_in[2];
    const float* s_eta  = (const float*)d_in[3];
    const float* s_zeta = (const float*)d_in[4];
    float* out = (float*)d_out;

    const int grid = 7812;  // 8*62*126*32 threads / 256
    hipLaunchKernelGGL(cns_residuals_kernel, dim3(grid), dim3(256), 0, stream,
                       vars, s_dx, s_dt, s_eta, s_zeta, out);
}